// Round 9
// baseline (316.870 us; speedup 1.0000x reference)
//
#include <hip/hip_runtime.h>
#include <math.h>

#define BB 64
#define TT 4096
#define CC 128
#define NQ 64
#define TCH 256   // t-rows per apply block
#define NBKT 2048 // bins for transposed-path select
#define NBKT_G 1024

// ---------------- Kernel 0: transpose x (B,T,C) -> xT (B,C,T) ----------------
__global__ __launch_bounds__(256) void transpose_kernel(const float* __restrict__ x,
                                                        float* __restrict__ xT) {
    __shared__ float tile[64][65];
    const int cb = blockIdx.x;        // c0 = cb*64 (0..1)
    const int tb = blockIdx.y;        // t0 = tb*64 (0..63)
    const int b  = blockIdx.z;
    const int tid = threadIdx.x;
    const int q = tid >> 6;           // 0..3
    const int l = tid & 63;

    const float* xs = x + ((size_t)b * TT + (size_t)tb * 64) * CC + (size_t)cb * 64;
    #pragma unroll
    for (int j = 0; j < 16; ++j) {
        int tl = q * 16 + j;
        tile[tl][l] = xs[(size_t)tl * CC + l];      // 64 consecutive c per instr
    }
    __syncthreads();
    float* xd = xT + ((size_t)b * CC + (size_t)cb * 64) * TT + (size_t)tb * 64;
    #pragma unroll
    for (int j = 0; j < 16; ++j) {
        int cl = q * 16 + j;
        xd[(size_t)cl * TT + l] = tile[l][cl];      // 64 consecutive t per instr
    }
}

// ---------------- Kernel 1 (fast path): contiguous-row bucket select ----------------
__global__ __launch_bounds__(256) void bucket_quantile_T(const float* __restrict__ xT,
                                                         float* __restrict__ qtab) {
    __shared__ unsigned cum[NBKT];
    __shared__ unsigned cur[NBKT];
    __shared__ float    pool[TT];
    __shared__ unsigned wsum[4];

    const int row = blockIdx.x;              // = b*CC + c
    const float* xrow = xT + (size_t)row * TT;
    const int tid = threadIdx.x, lane = tid & 63, wid = tid >> 6;

    // contiguous vector load: 16 elements per thread
    float vv[16];
    #pragma unroll
    for (int j = 0; j < 4; ++j) {
        float4 v4 = ((const float4*)xrow)[j * 256 + tid];
        vv[j * 4 + 0] = v4.x; vv[j * 4 + 1] = v4.y;
        vv[j * 4 + 2] = v4.z; vv[j * 4 + 3] = v4.w;
    }

    // zero histogram (8 bins per thread)
    *(uint4*)&cur[tid * 8]     = make_uint4(0u, 0u, 0u, 0u);
    *(uint4*)&cur[tid * 8 + 4] = make_uint4(0u, 0u, 0u, 0u);
    __syncthreads();

    // histogram: bucket = clamp(trunc((v+5)*204.8), 0, 2047) — monotone in v
    #pragma unroll
    for (int j = 0; j < 16; ++j) {
        int bk = (int)((vv[j] + 5.0f) * 204.8f);
        bk = bk < 0 ? 0 : (bk > NBKT - 1 ? NBKT - 1 : bk);
        atomicAdd(&cur[bk], 1u);
    }
    __syncthreads();

    // block-wide exclusive scan (thread owns 8 consecutive bins)
    uint4 h0 = *(uint4*)&cur[tid * 8];
    uint4 h1 = *(uint4*)&cur[tid * 8 + 4];
    unsigned S = h0.x + h0.y + h0.z + h0.w + h1.x + h1.y + h1.z + h1.w;
    unsigned incl = S;
    #pragma unroll
    for (int off = 1; off < 64; off <<= 1) {
        unsigned n = __shfl_up(incl, off, 64);
        if (lane >= off) incl += n;
    }
    if (lane == 63) wsum[wid] = incl;
    __syncthreads();
    unsigned base = incl - S;
    for (int w = 0; w < wid; ++w) base += wsum[w];
    {
        unsigned c0 = base, c1 = c0 + h0.x, c2 = c1 + h0.y, c3 = c2 + h0.z;
        unsigned c4 = c3 + h0.w, c5 = c4 + h1.x, c6 = c5 + h1.y, c7 = c6 + h1.z;
        *(uint4*)&cum[tid * 8]     = make_uint4(c0, c1, c2, c3);
        *(uint4*)&cum[tid * 8 + 4] = make_uint4(c4, c5, c6, c7);
        *(uint4*)&cur[tid * 8]     = make_uint4(c0, c1, c2, c3);
        *(uint4*)&cur[tid * 8 + 4] = make_uint4(c4, c5, c6, c7);
    }
    __syncthreads();

    // counting-scatter into value-partitioned pool
    #pragma unroll
    for (int j = 0; j < 16; ++j) {
        int bk = (int)((vv[j] + 5.0f) * 204.8f);
        bk = bk < 0 ? 0 : (bk > NBKT - 1 ? NBKT - 1 : bk);
        unsigned p = atomicAdd(&cur[bk], 1u);
        pool[p] = vv[j];
    }
    __syncthreads();

    // rank selection: ranks 64q+31 (+1); exact k-th smallest within segment
    if (tid < 128) {
        const int q = tid >> 1;
        const int r = (q << 6) + 31 + (tid & 1);

        int pos = 0;
        #pragma unroll
        for (int step = 1024; step >= 1; step >>= 1) {
            int np = pos + step;
            if (np <= NBKT - 1 && (int)cum[np] <= r) pos = np;
        }
        const int segbase = (int)cum[pos];
        const int L = ((pos == NBKT - 1) ? TT : (int)cum[pos + 1]) - segbase;
        const int k = r - segbase;
        const float* seg = &pool[segbase];

        float ans = 0.0f;
        for (int i = 0; i < L; ++i) {
            float vi = seg[i];
            int rk = 0;
            for (int jj = 0; jj < L; ++jj) {
                float vj = seg[jj];
                rk += (vj < vi) || (vj == vi && jj < i);   // index tie-break
            }
            if (rk == k) { ans = vi; break; }
        }
        float vo = __shfl_xor(ans, 1, 64);
        if ((tid & 1) == 0)
            qtab[(size_t)row * NQ + q] = (ans + vo) * 0.5f;  // frac = 0.5 exactly
    }
}

// ---------------- Kernel 1 (fallback, proven R7): strided-gather bucket select ----------------
__global__ __launch_bounds__(256) void bucket_quantile_G(const float* __restrict__ x,
                                                         float* __restrict__ qtab) {
    __shared__ unsigned hist[NBKT_G];
    __shared__ unsigned cum[NBKT_G];
    __shared__ unsigned cur[NBKT_G];
    __shared__ float    pool[TT];
    __shared__ unsigned wsum[4];

    const int bid = blockIdx.x;
    const int row = ((bid & 7) << 10) | (bid >> 3);
    const int b = row >> 7, c = row & (CC - 1);
    const float* xrow = x + (size_t)b * TT * CC + c;
    const int tid = threadIdx.x;
    const int lane = tid & 63, wid = tid >> 6;

    float vv[16];
    #pragma unroll
    for (int j = 0; j < 16; ++j)
        vv[j] = xrow[(size_t)((j << 8) + tid) * CC];

    *(uint4*)&hist[tid << 2] = make_uint4(0u, 0u, 0u, 0u);
    __syncthreads();

    #pragma unroll
    for (int j = 0; j < 16; ++j) {
        int bk = (int)((vv[j] + 5.0f) * 102.4f);
        bk = bk < 0 ? 0 : (bk > NBKT_G - 1 ? NBKT_G - 1 : bk);
        atomicAdd(&hist[bk], 1u);
    }
    __syncthreads();

    uint4 h = *(uint4*)&hist[tid << 2];
    unsigned S = h.x + h.y + h.z + h.w;
    unsigned incl = S;
    #pragma unroll
    for (int off = 1; off < 64; off <<= 1) {
        unsigned n = __shfl_up(incl, off, 64);
        if (lane >= off) incl += n;
    }
    if (lane == 63) wsum[wid] = incl;
    __syncthreads();
    unsigned base = incl - S;
    for (int w = 0; w < wid; ++w) base += wsum[w];
    {
        unsigned c0 = base, c1 = c0 + h.x, c2 = c1 + h.y, c3 = c2 + h.z;
        *(uint4*)&cum[tid << 2] = make_uint4(c0, c1, c2, c3);
        *(uint4*)&cur[tid << 2] = make_uint4(c0, c1, c2, c3);
    }
    __syncthreads();

    #pragma unroll
    for (int j = 0; j < 16; ++j) {
        int bk = (int)((vv[j] + 5.0f) * 102.4f);
        bk = bk < 0 ? 0 : (bk > NBKT_G - 1 ? NBKT_G - 1 : bk);
        unsigned p = atomicAdd(&cur[bk], 1u);
        pool[p] = vv[j];
    }
    __syncthreads();

    if (tid < 128) {
        const int q = tid >> 1;
        const int r = (q << 6) + 31 + (tid & 1);
        int pos = 0;
        #pragma unroll
        for (int step = 512; step >= 1; step >>= 1) {
            int np = pos + step;
            if (np <= NBKT_G - 1 && (int)cum[np] <= r) pos = np;
        }
        const int segbase = (int)cum[pos];
        const int L = (int)hist[pos];
        const int k = r - segbase;
        const float* seg = &pool[segbase];

        float ans = 0.0f;
        for (int i = 0; i < L; ++i) {
            float vi = seg[i];
            int rk = 0;
            for (int jj = 0; jj < L; ++jj) {
                float vj = seg[jj];
                rk += (vj < vi) || (vj == vi && jj < i);
            }
            if (rk == k) { ans = vi; break; }
        }
        float vo = __shfl_xor(ans, 1, 64);
        if ((tid & 1) == 0)
            qtab[(size_t)row * NQ + q] = (ans + vo) * 0.5f;
    }
}

// ---------------- Kernel 2: CDF interp + probit (Giles erfinv, qtT layout) ----------------
__global__ __launch_bounds__(256) void apply_kernel(const float* __restrict__ x,
                                                    const float* __restrict__ qtab,
                                                    float* __restrict__ out) {
    // Transposed table: bank = (k*128 + c) % 32 = c % 32 -> search reads are
    // conflict-free regardless of per-lane pos divergence (2 lanes/bank = free).
    __shared__ float qtT[NQ][CC];
    const int b = blockIdx.x;
    const int tch = blockIdx.y;
    const int tid = threadIdx.x;

    const float* qsrc = qtab + (size_t)b * CC * NQ;
    for (int i = tid; i < CC * NQ; i += 256) {
        // one-time staging; write conflicts here are negligible (32 wave-writes)
        qtT[i & (NQ - 1)][i >> 6] = qsrc[i];
    }
    __syncthreads();

    const size_t base = (size_t)b * TT * CC + (size_t)tch * TCH * CC;
    const float* xp = x + base;
    float* op = out + base;
    const float invq = 1.0f / (float)NQ;

    for (int i = tid; i < TCH * CC; i += 256) {
        const int cc = i & (CC - 1);
        const float v = xp[i];

        // searchsorted(side='right') capped at 63 (clip makes 64 == 63)
        int pos = 0;
        #pragma unroll
        for (int step = 32; step >= 1; step >>= 1) {
            int np = pos + step;
            pos = (qtT[np - 1][cc] <= v) ? np : pos;
        }
        int idx = pos;
        if (idx < 1) idx = 1;
        if (idx > NQ - 1) idx = NQ - 1;

        const float x0 = qtT[idx - 1][cc];
        const float x1 = qtT[idx][cc];
        const float y0 = ((float)idx - 0.5f) * invq;
        const float rcp = __builtin_amdgcn_rcpf(fmaxf(x1 - x0, 1e-12f));
        float p = fmaf(invq * rcp, v - x0, y0);
        p = fminf(fmaxf(p, 1e-6f), 1.0f - 1e-6f);

        // probit via Giles (2012) single-precision erfinv
        const float xx = 2.0f * p - 1.0f;
        float w = -__logf((1.0f - xx) * (1.0f + xx));
        float z;
        if (w < 5.0f) {
            float ww = w - 2.5f;
            z = 2.81022636e-08f;
            z = fmaf(z, ww, 3.43273939e-07f);
            z = fmaf(z, ww, -3.5233877e-06f);
            z = fmaf(z, ww, -4.39150654e-06f);
            z = fmaf(z, ww, 0.00021858087f);
            z = fmaf(z, ww, -0.00125372503f);
            z = fmaf(z, ww, -0.00417768164f);
            z = fmaf(z, ww, 0.246640727f);
            z = fmaf(z, ww, 1.50140941f);
        } else {
            float ww = sqrtf(w) - 3.0f;
            z = -0.000200214257f;
            z = fmaf(z, ww, 0.000100950558f);
            z = fmaf(z, ww, 0.00134934322f);
            z = fmaf(z, ww, -0.00367342844f);
            z = fmaf(z, ww, 0.00573950773f);
            z = fmaf(z, ww, -0.0076224613f);
            z = fmaf(z, ww, 0.00943887047f);
            z = fmaf(z, ww, 1.00167406f);
            z = fmaf(z, ww, 2.83297682f);
        }
        op[i] = z * xx * 1.4142135623730951f;   // erfinv(2p-1) * sqrt(2)
    }
}

extern "C" void kernel_launch(void* const* d_in, const int* in_sizes, int n_in,
                              void* d_out, int out_size, void* d_ws, size_t ws_size,
                              hipStream_t stream) {
    const float* x = (const float*)d_in[0];
    float* out = (float*)d_out;
    float* qtab = (float*)d_ws;                          // 2 MB
    const size_t qtab_bytes = (size_t)BB * CC * NQ * 4;
    const size_t xT_bytes   = (size_t)BB * CC * TT * 4;  // 128 MB

    if (ws_size >= qtab_bytes + xT_bytes) {
        float* xT = (float*)((char*)d_ws + qtab_bytes);
        dim3 tgrid(2, 64, BB);
        transpose_kernel<<<tgrid, 256, 0, stream>>>(x, xT);
        bucket_quantile_T<<<BB * CC, 256, 0, stream>>>(xT, qtab);
    } else {
        bucket_quantile_G<<<BB * CC, 256, 0, stream>>>(x, qtab);
    }
    dim3 grid(BB, TT / TCH);
    apply_kernel<<<grid, 256, 0, stream>>>(x, qtab, out);
}

// Round 10
// 247.166 us; speedup vs baseline: 1.2820x; 1.2820x over previous
//
#include <hip/hip_runtime.h>
#include <math.h>

#define BB 64
#define TT 4096
#define CC 128
#define NQ 64
#define TCH2 128  // t-rows per apply block (c is split 2-way)
#define NBKT 2048 // bins for transposed-path select
#define NBKT_G 1024

// ---------------- Kernel 0: transpose x (B,T,C) -> xT (B,C,T) ----------------
__global__ __launch_bounds__(256) void transpose_kernel(const float* __restrict__ x,
                                                        float* __restrict__ xT) {
    __shared__ float tile[64][65];
    const int cb = blockIdx.x;        // c0 = cb*64 (0..1)
    const int tb = blockIdx.y;        // t0 = tb*64 (0..63)
    const int b  = blockIdx.z;
    const int tid = threadIdx.x;
    const int q = tid >> 6;           // 0..3
    const int l = tid & 63;

    const float* xs = x + ((size_t)b * TT + (size_t)tb * 64) * CC + (size_t)cb * 64;
    #pragma unroll
    for (int j = 0; j < 16; ++j) {
        int tl = q * 16 + j;
        tile[tl][l] = xs[(size_t)tl * CC + l];      // 64 consecutive c per instr
    }
    __syncthreads();
    float* xd = xT + ((size_t)b * CC + (size_t)cb * 64) * TT + (size_t)tb * 64;
    #pragma unroll
    for (int j = 0; j < 16; ++j) {
        int cl = q * 16 + j;
        xd[(size_t)cl * TT + l] = tile[l][cl];      // 64 consecutive t per instr
    }
}

// ---------------- Kernel 1 (fast path): contiguous-row bucket select ----------------
__global__ __launch_bounds__(256) void bucket_quantile_T(const float* __restrict__ xT,
                                                         float* __restrict__ qtab) {
    __shared__ unsigned cum[NBKT];
    __shared__ unsigned cur[NBKT];
    __shared__ float    pool[TT];
    __shared__ unsigned wsum[4];

    const int row = blockIdx.x;              // = b*CC + c
    const float* xrow = xT + (size_t)row * TT;
    const int tid = threadIdx.x, lane = tid & 63, wid = tid >> 6;

    // contiguous vector load: 16 elements per thread
    float vv[16];
    #pragma unroll
    for (int j = 0; j < 4; ++j) {
        float4 v4 = ((const float4*)xrow)[j * 256 + tid];
        vv[j * 4 + 0] = v4.x; vv[j * 4 + 1] = v4.y;
        vv[j * 4 + 2] = v4.z; vv[j * 4 + 3] = v4.w;
    }

    // zero histogram (8 bins per thread)
    *(uint4*)&cur[tid * 8]     = make_uint4(0u, 0u, 0u, 0u);
    *(uint4*)&cur[tid * 8 + 4] = make_uint4(0u, 0u, 0u, 0u);
    __syncthreads();

    // histogram: bucket = clamp(trunc((v+5)*204.8), 0, 2047) — monotone in v
    #pragma unroll
    for (int j = 0; j < 16; ++j) {
        int bk = (int)((vv[j] + 5.0f) * 204.8f);
        bk = bk < 0 ? 0 : (bk > NBKT - 1 ? NBKT - 1 : bk);
        atomicAdd(&cur[bk], 1u);
    }
    __syncthreads();

    // block-wide exclusive scan (thread owns 8 consecutive bins)
    uint4 h0 = *(uint4*)&cur[tid * 8];
    uint4 h1 = *(uint4*)&cur[tid * 8 + 4];
    unsigned S = h0.x + h0.y + h0.z + h0.w + h1.x + h1.y + h1.z + h1.w;
    unsigned incl = S;
    #pragma unroll
    for (int off = 1; off < 64; off <<= 1) {
        unsigned n = __shfl_up(incl, off, 64);
        if (lane >= off) incl += n;
    }
    if (lane == 63) wsum[wid] = incl;
    __syncthreads();
    unsigned base = incl - S;
    for (int w = 0; w < wid; ++w) base += wsum[w];
    {
        unsigned c0 = base, c1 = c0 + h0.x, c2 = c1 + h0.y, c3 = c2 + h0.z;
        unsigned c4 = c3 + h0.w, c5 = c4 + h1.x, c6 = c5 + h1.y, c7 = c6 + h1.z;
        *(uint4*)&cum[tid * 8]     = make_uint4(c0, c1, c2, c3);
        *(uint4*)&cum[tid * 8 + 4] = make_uint4(c4, c5, c6, c7);
        *(uint4*)&cur[tid * 8]     = make_uint4(c0, c1, c2, c3);
        *(uint4*)&cur[tid * 8 + 4] = make_uint4(c4, c5, c6, c7);
    }
    __syncthreads();

    // counting-scatter into value-partitioned pool
    #pragma unroll
    for (int j = 0; j < 16; ++j) {
        int bk = (int)((vv[j] + 5.0f) * 204.8f);
        bk = bk < 0 ? 0 : (bk > NBKT - 1 ? NBKT - 1 : bk);
        unsigned p = atomicAdd(&cur[bk], 1u);
        pool[p] = vv[j];
    }
    __syncthreads();

    // rank selection: ranks 64q+31 (+1); exact k-th smallest within segment
    if (tid < 128) {
        const int q = tid >> 1;
        const int r = (q << 6) + 31 + (tid & 1);

        int pos = 0;
        #pragma unroll
        for (int step = 1024; step >= 1; step >>= 1) {
            int np = pos + step;
            if (np <= NBKT - 1 && (int)cum[np] <= r) pos = np;
        }
        const int segbase = (int)cum[pos];
        const int L = ((pos == NBKT - 1) ? TT : (int)cum[pos + 1]) - segbase;
        const int k = r - segbase;
        const float* seg = &pool[segbase];

        float ans = 0.0f;
        for (int i = 0; i < L; ++i) {
            float vi = seg[i];
            int rk = 0;
            for (int jj = 0; jj < L; ++jj) {
                float vj = seg[jj];
                rk += (vj < vi) || (vj == vi && jj < i);   // index tie-break
            }
            if (rk == k) { ans = vi; break; }
        }
        float vo = __shfl_xor(ans, 1, 64);
        if ((tid & 1) == 0)
            qtab[(size_t)row * NQ + q] = (ans + vo) * 0.5f;  // frac = 0.5 exactly
    }
}

// ---------------- Kernel 1 (fallback, proven R7): strided-gather bucket select ----------------
__global__ __launch_bounds__(256) void bucket_quantile_G(const float* __restrict__ x,
                                                         float* __restrict__ qtab) {
    __shared__ unsigned hist[NBKT_G];
    __shared__ unsigned cum[NBKT_G];
    __shared__ unsigned cur[NBKT_G];
    __shared__ float    pool[TT];
    __shared__ unsigned wsum[4];

    const int bid = blockIdx.x;
    const int row = ((bid & 7) << 10) | (bid >> 3);
    const int b = row >> 7, c = row & (CC - 1);
    const float* xrow = x + (size_t)b * TT * CC + c;
    const int tid = threadIdx.x;
    const int lane = tid & 63, wid = tid >> 6;

    float vv[16];
    #pragma unroll
    for (int j = 0; j < 16; ++j)
        vv[j] = xrow[(size_t)((j << 8) + tid) * CC];

    *(uint4*)&hist[tid << 2] = make_uint4(0u, 0u, 0u, 0u);
    __syncthreads();

    #pragma unroll
    for (int j = 0; j < 16; ++j) {
        int bk = (int)((vv[j] + 5.0f) * 102.4f);
        bk = bk < 0 ? 0 : (bk > NBKT_G - 1 ? NBKT_G - 1 : bk);
        atomicAdd(&hist[bk], 1u);
    }
    __syncthreads();

    uint4 h = *(uint4*)&hist[tid << 2];
    unsigned S = h.x + h.y + h.z + h.w;
    unsigned incl = S;
    #pragma unroll
    for (int off = 1; off < 64; off <<= 1) {
        unsigned n = __shfl_up(incl, off, 64);
        if (lane >= off) incl += n;
    }
    if (lane == 63) wsum[wid] = incl;
    __syncthreads();
    unsigned base = incl - S;
    for (int w = 0; w < wid; ++w) base += wsum[w];
    {
        unsigned c0 = base, c1 = c0 + h.x, c2 = c1 + h.y, c3 = c2 + h.z;
        *(uint4*)&cum[tid << 2] = make_uint4(c0, c1, c2, c3);
        *(uint4*)&cur[tid << 2] = make_uint4(c0, c1, c2, c3);
    }
    __syncthreads();

    #pragma unroll
    for (int j = 0; j < 16; ++j) {
        int bk = (int)((vv[j] + 5.0f) * 102.4f);
        bk = bk < 0 ? 0 : (bk > NBKT_G - 1 ? NBKT_G - 1 : bk);
        unsigned p = atomicAdd(&cur[bk], 1u);
        pool[p] = vv[j];
    }
    __syncthreads();

    if (tid < 128) {
        const int q = tid >> 1;
        const int r = (q << 6) + 31 + (tid & 1);
        int pos = 0;
        #pragma unroll
        for (int step = 512; step >= 1; step >>= 1) {
            int np = pos + step;
            if (np <= NBKT_G - 1 && (int)cum[np] <= r) pos = np;
        }
        const int segbase = (int)cum[pos];
        const int L = (int)hist[pos];
        const int k = r - segbase;
        const float* seg = &pool[segbase];

        float ans = 0.0f;
        for (int i = 0; i < L; ++i) {
            float vi = seg[i];
            int rk = 0;
            for (int jj = 0; jj < L; ++jj) {
                float vj = seg[jj];
                rk += (vj < vi) || (vj == vi && jj < i);
            }
            if (rk == k) { ans = vi; break; }
        }
        float vo = __shfl_xor(ans, 1, 64);
        if ((tid & 1) == 0)
            qtab[(size_t)row * NQ + q] = (ans + vo) * 0.5f;
    }
}

// ---------------- Kernel 2: CDF interp + probit (batched search, 64-c blocks) ----------------
// Each block: 64 c-columns (16 KB table), 128 t-rows. Thread's 32 elements all
// share column c = tid&63. Search batched 8-wide for memory-level parallelism.
// Table layout qtT[k][c^k]: staging writes (c fixed, k varies) AND search reads
// (c=lane, k divergent) both spread across banks.
__global__ __launch_bounds__(256) void apply_kernel(const float* __restrict__ x,
                                                    const float* __restrict__ qtab,
                                                    float* __restrict__ out) {
    __shared__ float qtT[NQ][64];
    const int b   = blockIdx.x;       // 0..63
    const int tch = blockIdx.y;       // 0..31
    const int ch  = blockIdx.z;       // 0..1
    const int tid = threadIdx.x;

    // stage 64 c-columns of the quantile table (coalesced global read)
    const float* qsrc = qtab + ((size_t)b * CC + (size_t)ch * 64) * NQ;
    for (int i = tid; i < 64 * NQ; i += 256) {
        int cl = i >> 6, k = i & 63;
        qtT[k][cl ^ k] = qsrc[i];
    }
    __syncthreads();

    const int myc = tid & 63;                       // fixed column per thread
    const int trow0 = tid >> 6;                     // 0..3
    const size_t base = (size_t)b * TT * CC + (size_t)tch * TCH2 * CC
                      + (size_t)ch * 64;
    const float* xp = x + base;
    float* op = out + base;
    const float invq = 1.0f / (float)NQ;

    #pragma unroll
    for (int g = 0; g < 4; ++g) {                   // 4 batches of 8 elements
        float v[8];
        int   pos[8];
        int   off[8];
        #pragma unroll
        for (int e = 0; e < 8; ++e) {
            int t = trow0 + 4 * (g * 8 + e);        // t in [0,128)
            off[e] = t * CC + myc;
            v[e] = xp[off[e]];
            pos[e] = 0;
        }

        // batched searchsorted(side='right'), capped at 63
        #pragma unroll
        for (int step = 32; step >= 1; step >>= 1) {
            float pr[8];
            #pragma unroll
            for (int e = 0; e < 8; ++e) {
                int np = pos[e] + step - 1;
                pr[e] = qtT[np][myc ^ np];
            }
            #pragma unroll
            for (int e = 0; e < 8; ++e)
                if (pr[e] <= v[e]) pos[e] += step;
        }

        float x0[8], x1[8];
        #pragma unroll
        for (int e = 0; e < 8; ++e) {
            int idx = pos[e];
            idx = idx < 1 ? 1 : (idx > NQ - 1 ? NQ - 1 : idx);
            pos[e] = idx;
            x0[e] = qtT[idx - 1][myc ^ (idx - 1)];
            x1[e] = qtT[idx][myc ^ idx];
        }

        #pragma unroll
        for (int e = 0; e < 8; ++e) {
            const float y0 = ((float)pos[e] - 0.5f) * invq;
            const float rcp = __builtin_amdgcn_rcpf(fmaxf(x1[e] - x0[e], 1e-12f));
            float p = fmaf(invq * rcp, v[e] - x0[e], y0);
            p = fminf(fmaxf(p, 1e-6f), 1.0f - 1e-6f);

            // probit via Giles (2012) single-precision erfinv
            const float xx = 2.0f * p - 1.0f;
            float w = -__logf((1.0f - xx) * (1.0f + xx));
            float z;
            if (w < 5.0f) {
                float ww = w - 2.5f;
                z = 2.81022636e-08f;
                z = fmaf(z, ww, 3.43273939e-07f);
                z = fmaf(z, ww, -3.5233877e-06f);
                z = fmaf(z, ww, -4.39150654e-06f);
                z = fmaf(z, ww, 0.00021858087f);
                z = fmaf(z, ww, -0.00125372503f);
                z = fmaf(z, ww, -0.00417768164f);
                z = fmaf(z, ww, 0.246640727f);
                z = fmaf(z, ww, 1.50140941f);
            } else {
                float ww = sqrtf(w) - 3.0f;
                z = -0.000200214257f;
                z = fmaf(z, ww, 0.000100950558f);
                z = fmaf(z, ww, 0.00134934322f);
                z = fmaf(z, ww, -0.00367342844f);
                z = fmaf(z, ww, 0.00573950773f);
                z = fmaf(z, ww, -0.0076224613f);
                z = fmaf(z, ww, 0.00943887047f);
                z = fmaf(z, ww, 1.00167406f);
                z = fmaf(z, ww, 2.83297682f);
            }
            op[off[e]] = z * xx * 1.4142135623730951f;   // erfinv(2p-1)*sqrt(2)
        }
    }
}

extern "C" void kernel_launch(void* const* d_in, const int* in_sizes, int n_in,
                              void* d_out, int out_size, void* d_ws, size_t ws_size,
                              hipStream_t stream) {
    const float* x = (const float*)d_in[0];
    float* out = (float*)d_out;
    float* qtab = (float*)d_ws;                          // 2 MB
    const size_t qtab_bytes = (size_t)BB * CC * NQ * 4;
    const size_t xT_bytes   = (size_t)BB * CC * TT * 4;  // 128 MB

    if (ws_size >= qtab_bytes + xT_bytes) {
        float* xT = (float*)((char*)d_ws + qtab_bytes);
        dim3 tgrid(2, 64, BB);
        transpose_kernel<<<tgrid, 256, 0, stream>>>(x, xT);
        bucket_quantile_T<<<BB * CC, 256, 0, stream>>>(xT, qtab);
    } else {
        bucket_quantile_G<<<BB * CC, 256, 0, stream>>>(x, qtab);
    }
    dim3 grid(BB, TT / TCH2, 2);
    apply_kernel<<<grid, 256, 0, stream>>>(x, qtab, out);
}